// Round 6
// baseline (770.245 us; speedup 1.0000x reference)
//
#include <hip/hip_runtime.h>
#include <hip/hip_bf16.h>

// MultiScaleRetention forward. Inputs/outputs FLOAT32; internals bf16 MFMA.
//   0) convert x -> xb (bf16); transpose weights f32 -> bf16
//   1) GEMM1 (m97-style, global_load_lds staging): xb @ Wt^T; LEAN epilogue:
//      qk cols -> f32 Cqk (+bias,+k-scale); v -> vT bf16; g -> f32
//   2) router: rotary (f32) + hi/lo bf16 split + (bh,S,64) layout for q,k
//   3) retention: split-precision QK^T (6 MFMAs) * decay-mask -> PV (bf16 P),
//      rowsum denom, groupnorm(128) + silu(g f32) gating -> gated bf16
//   4) GEMM2: gated @ oT^T + o_b -> d_out (f32)
//
// R6 changes vs R5 (retention was 470us: MfmaUtil 3.7%, latency-bound):
//   - single-wave (64-thr) blocks, m-tile = 127-bx (heaviest dispatched first)
//     -> dynamic load balance, kills the causal-imbalance tail
//   - K+V loads hoisted ABOVE the lgkm fence (V was issued after the memory
//     clobber every iter -> ~200cyc exposed latency x32 iters); V split 4+4
//     to stay under the 128-VGPR occupancy cliff
//   - QK split into 3 independent 2-deep MFMA chains (was one 6-deep chain)
//   - incremental decay: p = sc*rf[r]*cf[hh], rf *= gamma^-32 per tile
//     (removes 8 quarter-rate exp2f per iteration)

typedef __hip_bfloat16 bf16;
typedef short bf16x4 __attribute__((ext_vector_type(4)));
typedef short bf16x8 __attribute__((ext_vector_type(8)));
typedef float floatx4 __attribute__((ext_vector_type(4)));

#define B_SZ 2
#define SEQ 2048
#define NH 16
#define KD 64
#define HD 128

// global->LDS direct copy, 16B/lane. LDS dest is wave-uniform base + lane*16.
#define ASYNC16(gp, lp)                                                             \
  __builtin_amdgcn_global_load_lds(                                                 \
      (const __attribute__((address_space(1))) unsigned int*)(unsigned long long)(const void*)(gp), \
      (__attribute__((address_space(3))) unsigned int*)(unsigned int)(unsigned long long)(void*)(lp), \
      16, 0, 0)

__device__ __forceinline__ float b2f(bf16 x) { return __bfloat162float(x); }
__device__ __forceinline__ bf16 f2b(float x) { return __float2bfloat16(x); }

// ---------------- f32 -> bf16 convert (x) ----------------
__global__ void convert_k(const float* __restrict__ in, bf16* __restrict__ out) {
  int i = blockIdx.x * 256 + threadIdx.x;  // one float4 per thread
  float4 v = reinterpret_cast<const float4*>(in)[i];
  union { bf16 h[4]; bf16x4 v4; } u;
  u.h[0] = f2b(v.x); u.h[1] = f2b(v.y); u.h[2] = f2b(v.z); u.h[3] = f2b(v.w);
  reinterpret_cast<bf16x4*>(out)[i] = u.v4;
}

// ---------------- weight transpose: in f32 (K,N) -> out bf16 (N,K) --------
__global__ void transpose_k(const float* __restrict__ in, bf16* __restrict__ out,
                            int K, int N) {
  __shared__ float tile[32][33];
  int tx = threadIdx.x, ty = threadIdx.y;
  int n0 = blockIdx.x * 32, k0 = blockIdx.y * 32;
#pragma unroll
  for (int j = 0; j < 4; ++j)
    tile[ty + j * 8][tx] = in[(size_t)(k0 + ty + j * 8) * N + n0 + tx];
  __syncthreads();
#pragma unroll
  for (int j = 0; j < 4; ++j)
    out[(size_t)(n0 + ty + j * 8) * K + k0 + tx] = f2b(tile[tx][ty + j * 8]);
}

// ---------------- GEMM: C(M,N) = A(M,K) @ Bt(N,K)^T ----------------
// MODE 0: QKVG epilogue (bias; qk -> f32 Cqk; v -> vT bf16; g -> f32)
// MODE 1: output projection epilogue (f32 bias + f32 store)
template <int BM, int BN, int KDIM, int MODE>
__global__ __launch_bounds__(256, 2) void gemm_bt(
    const bf16* __restrict__ A, const bf16* __restrict__ Bt, int Ndim,
    const float* __restrict__ bias_q, const float* __restrict__ bias_k,
    const float* __restrict__ bias_v, const float* __restrict__ bias_g,
    float* __restrict__ outCqk, bf16* __restrict__ out_vT,
    float* __restrict__ out_g, float* __restrict__ outF) {
  __shared__ bf16 As[BM * 32];
  __shared__ bf16 Bs[BN * 32];
  const int tid = threadIdx.x;
  const int wave = tid >> 6, lane = tid & 63;
  const int quad = lane >> 4, l16 = lane & 15;
  const int m0 = blockIdx.y * BM, n0 = blockIdx.x * BN;
  constexpr int FI = BM / 32;
  constexpr int FJ = BN / 32;
  const int wm = (wave >> 1) * (BM / 2), wn = (wave & 1) * (BN / 2);

  floatx4 acc[FI][FJ] = {};

  for (int k0 = 0; k0 < KDIM; k0 += 32) {
#pragma unroll
    for (int j = 0; j < BM / 64; ++j) {
      int cbase = (j * 4 + wave) * 64;
      int c = cbase + lane;
      const bf16* g = A + (size_t)(m0 + (c >> 2)) * KDIM + k0 + (c & 3) * 8;
      ASYNC16(g, &As[cbase * 8]);
    }
#pragma unroll
    for (int j = 0; j < BN / 64; ++j) {
      int cbase = (j * 4 + wave) * 64;
      int c = cbase + lane;
      const bf16* g = Bt + (size_t)(n0 + (c >> 2)) * KDIM + k0 + (c & 3) * 8;
      ASYNC16(g, &Bs[cbase * 8]);
    }
    __syncthreads();  // compiler drains vmcnt(0) before s_barrier

    bf16x8 af[FI], bfr[FJ];
#pragma unroll
    for (int i = 0; i < FI; ++i)
      af[i] = *(const bf16x8*)&As[(wm + i * 16 + l16) * 32 + quad * 8];
#pragma unroll
    for (int j = 0; j < FJ; ++j)
      bfr[j] = *(const bf16x8*)&Bs[(wn + j * 16 + l16) * 32 + quad * 8];
#pragma unroll
    for (int i = 0; i < FI; ++i)
#pragma unroll
      for (int j = 0; j < FJ; ++j)
        acc[i][j] = __builtin_amdgcn_mfma_f32_16x16x32_bf16(af[i], bfr[j],
                                                            acc[i][j], 0, 0, 0);
    __syncthreads();
  }

  // LEAN epilogue: C layout col=lane&15 (n), row=quad*4+r (m)
#pragma unroll
  for (int i = 0; i < FI; ++i) {
#pragma unroll
    for (int j = 0; j < FJ; ++j) {
#pragma unroll
      for (int r = 0; r < 4; ++r) {
        int gm = m0 + wm + i * 16 + quad * 4 + r;
        int gn = n0 + wn + j * 16 + l16;
        float v = acc[i][j][r];
        if (MODE == 1) {
          v += bias_q[gn];  // bias_q = o_b
          outF[(size_t)gm * Ndim + gn] = v;
        } else {
          int b = gm >> 11, s = gm & 2047;
          if (gn < 2048) {
            bool is_k = gn >= 1024;
            int jj = is_k ? gn - 1024 : gn;
            v += is_k ? bias_k[jj] : bias_q[jj];
            if (is_k) v *= 0.125f;  // SCALING = KEY_DIM^-0.5
            outCqk[(size_t)gm * 2048 + gn] = v;  // f32, exact
          } else if (gn < 4096) {
            int jj = gn - 2048;
            v += bias_v[jj];
            int h = jj >> 7, d = jj & 127;
            out_vT[(((size_t)b * NH + h) * HD + d) * SEQ + s] = f2b(v);
          } else {
            int jj = gn - 4096;
            v += bias_g[jj];
            out_g[(size_t)gm * 2048 + jj] = v;  // f32
          }
        }
      }
    }
  }
}

// ---------------- router: rotary + hi/lo split + layout ----------------
// one thread per rotary pair; Cqk (4096, 2048) f32: cols 0..1023 q, 1024.. k
__global__ void router_k(const float* __restrict__ Cqk,
                         bf16* __restrict__ qh, bf16* __restrict__ ql,
                         bf16* __restrict__ kh, bf16* __restrict__ kl) {
  int t = blockIdx.x * 256 + threadIdx.x;  // 4096*1024 threads
  int row = t >> 10, pc = t & 1023;
  int b = row >> 11, s = row & 2047;
  bool is_k = pc >= 512;
  int jj = (pc - (is_k ? 512 : 0)) * 2;  // even, 0..1022
  int h = jj >> 6, d = jj & 63, ii = d >> 1;
  float2 v = *(const float2*)&Cqk[(size_t)row * 2048 + pc * 2];
  // half[ii] = 10000^(-ii/31); ang = s * half[ii]
  float half = exp2f(-(float)ii * (13.287712379549449f / 31.0f));
  float ang = (float)s * half;
  float sn = sinf(ang), cs = cosf(ang);
  float e = v.x * cs - v.y * sn;   // even:  x[2i]c   - x[2i+1]s
  float o = v.y * cs + v.x * sn;   // odd:   x[2i+1]c + x[2i]s
  bf16 eh = f2b(e), oh = f2b(o);
  bf16 el = f2b(e - b2f(eh)), ol = f2b(o - b2f(oh));
  size_t idx = (((size_t)b * NH + h) * SEQ + s) * KD + d;  // d even -> 4B align
  bf16* ph = is_k ? kh : qh;
  bf16* pl = is_k ? kl : ql;
  union { bf16 h2[2]; unsigned u; } uh, ul;
  uh.h2[0] = eh; uh.h2[1] = oh;
  ul.h2[0] = el; ul.h2[1] = ol;
  *(unsigned*)&ph[idx] = uh.u;
  *(unsigned*)&pl[idx] = ul.u;
}

// ---------------- retention core ----------------
// ONE WAVE per block (64 thr), 16 Q-rows per block. grid (128, NH, B) with
// m-tile = 127-bx so the heaviest (most causal n-tiles) blocks dispatch
// first -> dynamic load balance. Per-wave LDS P round-trip; the asm fence
// is both the lgkm drain AND the compiler barrier for cross-lane LDS
// communication. K/V loads are issued ABOVE the fence so their latency is
// hidden by the QK/mask phase.
__global__ __launch_bounds__(64, 4) void retention_k(
    const bf16* __restrict__ qh, const bf16* __restrict__ ql,
    const bf16* __restrict__ kh, const bf16* __restrict__ kl,
    const bf16* __restrict__ vT, const float* __restrict__ g,
    bf16* __restrict__ gated) {
  __shared__ bf16 Pl[16 * 32];  // P tile (C-layout -> A-layout)
  const int lane = threadIdx.x;
  const int quad = lane >> 4, l16 = lane & 15;
  const int h = blockIdx.y, b = blockIdx.z;
  const int bh = b * NH + h;
  const int mt = 127 - blockIdx.x;  // heavy-first
  const int m0 = mt * 16;

  const float t = exp2f(-(float)(5 + h));  // 1-gamma (exact)
  const float lng = log1pf(-t);            // ln(gamma)
  const float log2g = lng * 1.44269504088896340736f;

  // rf[r] = gamma^(m-n0) * inv_ms[r], updated by *gamma^-32 per tile.
  // inv_ms = 1/sqrt((1-gamma^(m+1))/(1-gamma)); expm1 avoids cancellation.
  float rf[4];
#pragma unroll
  for (int r = 0; r < 4; ++r) {
    int m = m0 + quad * 4 + r;
    float num = -expm1f((float)(m + 1) * lng);
    rf[r] = exp2f((float)m * log2g) * rsqrtf(num / t);
  }
  const float gstep = exp2f(-32.0f * log2g);            // gamma^-32
  const float cf0 = exp2f(-(float)l16 * log2g);         // gamma^-l16
  const float cf1 = cf0 * exp2f(-16.0f * log2g);        // gamma^-(16+l16)

  const size_t qoff = ((size_t)bh * SEQ + m0 + l16) * KD;
  bf16x8 aq0h = *(const bf16x8*)&qh[qoff + quad * 8];
  bf16x8 aq1h = *(const bf16x8*)&qh[qoff + 32 + quad * 8];
  bf16x8 aq0l = *(const bf16x8*)&ql[qoff + quad * 8];
  bf16x8 aq1l = *(const bf16x8*)&ql[qoff + 32 + quad * 8];

  floatx4 oacc[8] = {};
  float rowsum[4] = {0.f, 0.f, 0.f, 0.f};

  const bf16* khb = kh + (size_t)bh * SEQ * KD;
  const bf16* klb = kl + (size_t)bh * SEQ * KD;
  const bf16* vbase = vT + (size_t)bh * HD * SEQ;
  const int ntiles = (m0 >> 5) + 1;

  for (int nt = 0; nt < ntiles; ++nt) {
    const int n0 = nt * 32;
    // ---- issue K loads (8 x b128) ----
    const size_t k0off = (size_t)(n0 + l16) * KD + quad * 8;
    const size_t k1off = (size_t)(n0 + 16 + l16) * KD + quad * 8;
    bf16x8 bk0h = *(const bf16x8*)&khb[k0off];
    bf16x8 bk0h2 = *(const bf16x8*)&khb[k0off + 32];
    bf16x8 bk0l = *(const bf16x8*)&klb[k0off];
    bf16x8 bk0l2 = *(const bf16x8*)&klb[k0off + 32];
    bf16x8 bk1h = *(const bf16x8*)&khb[k1off];
    bf16x8 bk1h2 = *(const bf16x8*)&khb[k1off + 32];
    bf16x8 bk1l = *(const bf16x8*)&klb[k1off];
    bf16x8 bk1l2 = *(const bf16x8*)&klb[k1off + 32];
    // ---- issue first half of V loads (latency hidden by QK+mask) ----
    bf16x8 bv[4];
#pragma unroll
    for (int dt = 0; dt < 4; ++dt)
      bv[dt] = *(const bf16x8*)&vbase[(size_t)(dt * 16 + l16) * SEQ + n0 + quad * 8];

    // ---- QK: 3 independent 2-deep chains per half ----
    floatx4 sc[2];
    {
      floatx4 z1 = {0.f, 0.f, 0.f, 0.f}, z2 = z1, z3 = z1;
      z1 = __builtin_amdgcn_mfma_f32_16x16x32_bf16(aq0h, bk0h, z1, 0, 0, 0);
      z2 = __builtin_amdgcn_mfma_f32_16x16x32_bf16(aq0l, bk0h, z2, 0, 0, 0);
      z3 = __builtin_amdgcn_mfma_f32_16x16x32_bf16(aq0h, bk0l, z3, 0, 0, 0);
      z1 = __builtin_amdgcn_mfma_f32_16x16x32_bf16(aq1h, bk0h2, z1, 0, 0, 0);
      z2 = __builtin_amdgcn_mfma_f32_16x16x32_bf16(aq1l, bk0h2, z2, 0, 0, 0);
      z3 = __builtin_amdgcn_mfma_f32_16x16x32_bf16(aq1h, bk0l2, z3, 0, 0, 0);
      sc[0] = z1 + z2 + z3;
    }
    {
      floatx4 z1 = {0.f, 0.f, 0.f, 0.f}, z2 = z1, z3 = z1;
      z1 = __builtin_amdgcn_mfma_f32_16x16x32_bf16(aq0h, bk1h, z1, 0, 0, 0);
      z2 = __builtin_amdgcn_mfma_f32_16x16x32_bf16(aq0l, bk1h, z2, 0, 0, 0);
      z3 = __builtin_amdgcn_mfma_f32_16x16x32_bf16(aq0h, bk1l, z3, 0, 0, 0);
      z1 = __builtin_amdgcn_mfma_f32_16x16x32_bf16(aq1h, bk1h2, z1, 0, 0, 0);
      z2 = __builtin_amdgcn_mfma_f32_16x16x32_bf16(aq1l, bk1h2, z2, 0, 0, 0);
      z3 = __builtin_amdgcn_mfma_f32_16x16x32_bf16(aq1h, bk1l2, z3, 0, 0, 0);
      sc[1] = z1 + z2 + z3;
    }

    // ---- decay mask (incremental, no exp2) + row sums + stage P ----
#pragma unroll
    for (int hh = 0; hh < 2; ++hh) {
      float cf = hh ? cf1 : cf0;
#pragma unroll
      for (int r = 0; r < 4; ++r) {
        int m = m0 + quad * 4 + r;
        int n = n0 + hh * 16 + l16;
        float p = (m >= n) ? sc[hh][r] * rf[r] * cf : 0.f;
        rowsum[r] += p;
        Pl[(quad * 4 + r) * 32 + hh * 16 + l16] = f2b(p);
      }
    }
#pragma unroll
    for (int r = 0; r < 4; ++r) rf[r] *= gstep;

    // compiler barrier + lgkm drain: cross-lane LDS RAW (does NOT drain vmcnt,
    // so the K/V loads above keep their latency hidden)
    asm volatile("s_waitcnt lgkmcnt(0)" ::: "memory");
    bf16x8 pa = *(const bf16x8*)&Pl[l16 * 32 + quad * 8];

    // ---- second half of V loads (hidden by PV 0..3) ----
    bf16x8 bv2[4];
#pragma unroll
    for (int dt = 0; dt < 4; ++dt)
      bv2[dt] = *(const bf16x8*)&vbase[(size_t)((dt + 4) * 16 + l16) * SEQ + n0 + quad * 8];

#pragma unroll
    for (int dt = 0; dt < 4; ++dt)
      oacc[dt] = __builtin_amdgcn_mfma_f32_16x16x32_bf16(pa, bv[dt], oacc[dt], 0, 0, 0);
#pragma unroll
    for (int dt = 0; dt < 4; ++dt)
      oacc[dt + 4] = __builtin_amdgcn_mfma_f32_16x16x32_bf16(pa, bv2[dt], oacc[dt + 4], 0, 0, 0);
  }

  // denom = clip(|row sum|, 1); groupnorm over 128 dims; silu gate
  float inv_den[4];
#pragma unroll
  for (int r = 0; r < 4; ++r) {
    float v = rowsum[r];
    v += __shfl_xor(v, 1);
    v += __shfl_xor(v, 2);
    v += __shfl_xor(v, 4);
    v += __shfl_xor(v, 8);
    inv_den[r] = 1.0f / fmaxf(fabsf(v), 1.0f);
  }
  float s1[4] = {}, s2[4] = {};
#pragma unroll
  for (int dt = 0; dt < 8; ++dt) {
#pragma unroll
    for (int r = 0; r < 4; ++r) {
      float v = oacc[dt][r] * inv_den[r];
      oacc[dt][r] = v;
      s1[r] += v;
      s2[r] += v * v;
    }
  }
  float mean[4], istd[4];
#pragma unroll
  for (int r = 0; r < 4; ++r) {
    float a = s1[r], q2 = s2[r];
    a += __shfl_xor(a, 1); a += __shfl_xor(a, 2);
    a += __shfl_xor(a, 4); a += __shfl_xor(a, 8);
    q2 += __shfl_xor(q2, 1); q2 += __shfl_xor(q2, 2);
    q2 += __shfl_xor(q2, 4); q2 += __shfl_xor(q2, 8);
    mean[r] = a * (1.0f / 128.0f);
    float var = q2 * (1.0f / 128.0f) - mean[r] * mean[r];
    istd[r] = rsqrtf(fmaxf(var, 0.0f) + 1e-5f);
  }
#pragma unroll
  for (int dt = 0; dt < 8; ++dt) {
#pragma unroll
    for (int r = 0; r < 4; ++r) {
      int m = m0 + quad * 4 + r;
      int col = h * HD + dt * 16 + l16;
      float v = (oacc[dt][r] - mean[r]) * istd[r];
      float gv = g[((size_t)b * SEQ + m) * 2048 + col];
      float sg = gv / (1.0f + expf(-gv));
      gated[((size_t)b * SEQ + m) * 2048 + col] = f2b(sg * v);
    }
  }
}

// ---------------- launch ----------------
extern "C" void kernel_launch(void* const* d_in, const int* in_sizes, int n_in,
                              void* d_out, int out_size, void* d_ws,
                              size_t ws_size, hipStream_t stream) {
  const float* x   = (const float*)d_in[0];
  const float* q_w = (const float*)d_in[1];
  const float* q_b = (const float*)d_in[2];
  const float* k_w = (const float*)d_in[3];
  const float* k_b = (const float*)d_in[4];
  const float* v_w = (const float*)d_in[5];
  const float* v_b = (const float*)d_in[6];
  const float* g_w = (const float*)d_in[7];
  const float* g_b = (const float*)d_in[8];
  const float* o_w = (const float*)d_in[9];
  const float* o_b = (const float*)d_in[10];

  char* ws = (char*)d_ws;
  bf16* Wt    = (bf16*)ws; ws += (size_t)6144 * 1024 * 2;
  bf16* oT    = (bf16*)ws; ws += (size_t)1024 * 2048 * 2;
  bf16* xb    = (bf16*)ws; ws += (size_t)4096 * 1024 * 2;
  float* Cqk  = (float*)ws; ws += (size_t)4096 * 2048 * 4;
  bf16* qhb   = (bf16*)ws; ws += (size_t)32 * 2048 * 64 * 2;
  bf16* qlb   = (bf16*)ws; ws += (size_t)32 * 2048 * 64 * 2;
  bf16* khb   = (bf16*)ws; ws += (size_t)32 * 2048 * 64 * 2;
  bf16* klb   = (bf16*)ws; ws += (size_t)32 * 2048 * 64 * 2;
  bf16* vTb   = (bf16*)ws; ws += (size_t)32 * 128 * 2048 * 2;
  float* gbuf = (float*)ws; ws += (size_t)2 * 2048 * 2048 * 4;
  bf16* gated = (bf16*)ws; ws += (size_t)4096 * 2048 * 2;

  convert_k<<<(4096 * 1024 / 4) / 256, 256, 0, stream>>>(x, xb);

  dim3 tb(32, 8);
  transpose_k<<<dim3(1024 / 32, 1024 / 32), tb, 0, stream>>>(q_w, Wt, 1024, 1024);
  transpose_k<<<dim3(1024 / 32, 1024 / 32), tb, 0, stream>>>(k_w, Wt + (size_t)1024 * 1024, 1024, 1024);
  transpose_k<<<dim3(2048 / 32, 1024 / 32), tb, 0, stream>>>(v_w, Wt + (size_t)2048 * 1024, 1024, 2048);
  transpose_k<<<dim3(2048 / 32, 1024 / 32), tb, 0, stream>>>(g_w, Wt + (size_t)4096 * 1024, 1024, 2048);
  transpose_k<<<dim3(1024 / 32, 2048 / 32), tb, 0, stream>>>(o_w, oT, 2048, 1024);

  gemm_bt<128, 128, 1024, 0><<<dim3(6144 / 128, 4096 / 128), 256, 0, stream>>>(
      xb, Wt, 6144, q_b, k_b, v_b, g_b, Cqk, vTb, gbuf, nullptr);

  router_k<<<(4096 * 1024) / 256, 256, 0, stream>>>(Cqk, qhb, qlb, khb, klb);

  retention_k<<<dim3(128, NH, B_SZ), 64, 0, stream>>>(
      qhb, qlb, khb, klb, vTb, gbuf, gated);

  gemm_bt<128, 64, 2048, 1><<<dim3(1024 / 64, 4096 / 128), 256, 0, stream>>>(
      gated, oT, 1024, o_b, nullptr, nullptr, nullptr, nullptr, nullptr,
      nullptr, (float*)d_out);
}

// Round 7
// 379.375 us; speedup vs baseline: 2.0303x; 2.0303x over previous
//
#include <hip/hip_runtime.h>
#include <hip/hip_bf16.h>

// MultiScaleRetention forward. Inputs/outputs FLOAT32; internals bf16 MFMA.
//   0) convert x -> xb (bf16); transpose weights f32 -> bf16
//   1) GEMM1 (m97-style, global_load_lds staging): xb @ Wt^T; LEAN epilogue:
//      qk cols -> f32 Cqk (+bias,+k-scale); v -> vT bf16; g -> f32
//   2) router: rotary (f32) + hi/lo bf16 split + (bh,S,64) layout for q,k
//   3) retention: 4-wave blocks, K/V staged in LDS (shared by all waves),
//      split-precision QK^T -> decay-mask -> PV; groupnorm+silu fused
//   4) GEMM2: gated @ oT^T + o_b -> d_out (f32)
//
// R7 changes vs R6 (retention 524us: FETCH 505MB - L2 locality destroyed by
// 128 blocks/bh each streaming full K/V):
//   - retention: grid back to 32 m-tiles/bh (heavy-first), 256-thr blocks;
//     64-row Q-stripe/block; all 4 waves share one K/V LDS tile per n-tile
//     (global_load_lds width=16, chunk-swizzled so b128 frag reads are 2-way)
//     -> requested K/V bytes /4 vs R5, /16 vs R6
//   - __syncthreads legal now (uniform trip count; causality via mask;
//     fully-masked prefix guarded by `active`)
//   - keeps R6 ILP fixes (3 QK chains, incremental decay, no per-iter exp2)

typedef __hip_bfloat16 bf16;
typedef short bf16x4 __attribute__((ext_vector_type(4)));
typedef short bf16x8 __attribute__((ext_vector_type(8)));
typedef float floatx4 __attribute__((ext_vector_type(4)));

#define B_SZ 2
#define SEQ 2048
#define NH 16
#define KD 64
#define HD 128

// global->LDS direct copy, 16B/lane. LDS dest is wave-uniform base + lane*16.
#define ASYNC16(gp, lp)                                                             \
  __builtin_amdgcn_global_load_lds(                                                 \
      (const __attribute__((address_space(1))) unsigned int*)(unsigned long long)(const void*)(gp), \
      (__attribute__((address_space(3))) unsigned int*)(unsigned int)(unsigned long long)(void*)(lp), \
      16, 0, 0)

__device__ __forceinline__ float b2f(bf16 x) { return __bfloat162float(x); }
__device__ __forceinline__ bf16 f2b(float x) { return __float2bfloat16(x); }

// ---------------- f32 -> bf16 convert (x) ----------------
__global__ void convert_k(const float* __restrict__ in, bf16* __restrict__ out) {
  int i = blockIdx.x * 256 + threadIdx.x;  // one float4 per thread
  float4 v = reinterpret_cast<const float4*>(in)[i];
  union { bf16 h[4]; bf16x4 v4; } u;
  u.h[0] = f2b(v.x); u.h[1] = f2b(v.y); u.h[2] = f2b(v.z); u.h[3] = f2b(v.w);
  reinterpret_cast<bf16x4*>(out)[i] = u.v4;
}

// ---------------- weight transpose: in f32 (K,N) -> out bf16 (N,K) --------
__global__ void transpose_k(const float* __restrict__ in, bf16* __restrict__ out,
                            int K, int N) {
  __shared__ float tile[32][33];
  int tx = threadIdx.x, ty = threadIdx.y;
  int n0 = blockIdx.x * 32, k0 = blockIdx.y * 32;
#pragma unroll
  for (int j = 0; j < 4; ++j)
    tile[ty + j * 8][tx] = in[(size_t)(k0 + ty + j * 8) * N + n0 + tx];
  __syncthreads();
#pragma unroll
  for (int j = 0; j < 4; ++j)
    out[(size_t)(n0 + ty + j * 8) * K + k0 + tx] = f2b(tile[tx][ty + j * 8]);
}

// ---------------- GEMM: C(M,N) = A(M,K) @ Bt(N,K)^T ----------------
// MODE 0: QKVG epilogue (bias; qk -> f32 Cqk; v -> vT bf16; g -> f32)
// MODE 1: output projection epilogue (f32 bias + f32 store)
template <int BM, int BN, int KDIM, int MODE>
__global__ __launch_bounds__(256, 2) void gemm_bt(
    const bf16* __restrict__ A, const bf16* __restrict__ Bt, int Ndim,
    const float* __restrict__ bias_q, const float* __restrict__ bias_k,
    const float* __restrict__ bias_v, const float* __restrict__ bias_g,
    float* __restrict__ outCqk, bf16* __restrict__ out_vT,
    float* __restrict__ out_g, float* __restrict__ outF) {
  __shared__ bf16 As[BM * 32];
  __shared__ bf16 Bs[BN * 32];
  const int tid = threadIdx.x;
  const int wave = tid >> 6, lane = tid & 63;
  const int quad = lane >> 4, l16 = lane & 15;
  const int m0 = blockIdx.y * BM, n0 = blockIdx.x * BN;
  constexpr int FI = BM / 32;
  constexpr int FJ = BN / 32;
  const int wm = (wave >> 1) * (BM / 2), wn = (wave & 1) * (BN / 2);

  floatx4 acc[FI][FJ] = {};

  for (int k0 = 0; k0 < KDIM; k0 += 32) {
#pragma unroll
    for (int j = 0; j < BM / 64; ++j) {
      int cbase = (j * 4 + wave) * 64;
      int c = cbase + lane;
      const bf16* g = A + (size_t)(m0 + (c >> 2)) * KDIM + k0 + (c & 3) * 8;
      ASYNC16(g, &As[cbase * 8]);
    }
#pragma unroll
    for (int j = 0; j < BN / 64; ++j) {
      int cbase = (j * 4 + wave) * 64;
      int c = cbase + lane;
      const bf16* g = Bt + (size_t)(n0 + (c >> 2)) * KDIM + k0 + (c & 3) * 8;
      ASYNC16(g, &Bs[cbase * 8]);
    }
    __syncthreads();  // compiler drains vmcnt(0) before s_barrier

    bf16x8 af[FI], bfr[FJ];
#pragma unroll
    for (int i = 0; i < FI; ++i)
      af[i] = *(const bf16x8*)&As[(wm + i * 16 + l16) * 32 + quad * 8];
#pragma unroll
    for (int j = 0; j < FJ; ++j)
      bfr[j] = *(const bf16x8*)&Bs[(wn + j * 16 + l16) * 32 + quad * 8];
#pragma unroll
    for (int i = 0; i < FI; ++i)
#pragma unroll
      for (int j = 0; j < FJ; ++j)
        acc[i][j] = __builtin_amdgcn_mfma_f32_16x16x32_bf16(af[i], bfr[j],
                                                            acc[i][j], 0, 0, 0);
    __syncthreads();
  }

  // LEAN epilogue: C layout col=lane&15 (n), row=quad*4+r (m)
#pragma unroll
  for (int i = 0; i < FI; ++i) {
#pragma unroll
    for (int j = 0; j < FJ; ++j) {
#pragma unroll
      for (int r = 0; r < 4; ++r) {
        int gm = m0 + wm + i * 16 + quad * 4 + r;
        int gn = n0 + wn + j * 16 + l16;
        float v = acc[i][j][r];
        if (MODE == 1) {
          v += bias_q[gn];  // bias_q = o_b
          outF[(size_t)gm * Ndim + gn] = v;
        } else {
          int b = gm >> 11, s = gm & 2047;
          if (gn < 2048) {
            bool is_k = gn >= 1024;
            int jj = is_k ? gn - 1024 : gn;
            v += is_k ? bias_k[jj] : bias_q[jj];
            if (is_k) v *= 0.125f;  // SCALING = KEY_DIM^-0.5
            outCqk[(size_t)gm * 2048 + gn] = v;  // f32, exact
          } else if (gn < 4096) {
            int jj = gn - 2048;
            v += bias_v[jj];
            int h = jj >> 7, d = jj & 127;
            out_vT[(((size_t)b * NH + h) * HD + d) * SEQ + s] = f2b(v);
          } else {
            int jj = gn - 4096;
            v += bias_g[jj];
            out_g[(size_t)gm * 2048 + jj] = v;  // f32
          }
        }
      }
    }
  }
}

// ---------------- router: rotary + hi/lo split + layout ----------------
// one thread per rotary pair; Cqk (4096, 2048) f32: cols 0..1023 q, 1024.. k
__global__ void router_k(const float* __restrict__ Cqk,
                         bf16* __restrict__ qh, bf16* __restrict__ ql,
                         bf16* __restrict__ kh, bf16* __restrict__ kl) {
  int t = blockIdx.x * 256 + threadIdx.x;  // 4096*1024 threads
  int row = t >> 10, pc = t & 1023;
  int b = row >> 11, s = row & 2047;
  bool is_k = pc >= 512;
  int jj = (pc - (is_k ? 512 : 0)) * 2;  // even, 0..1022
  int h = jj >> 6, d = jj & 63, ii = d >> 1;
  float2 v = *(const float2*)&Cqk[(size_t)row * 2048 + pc * 2];
  // half[ii] = 10000^(-ii/31); ang = s * half[ii]
  float half = exp2f(-(float)ii * (13.287712379549449f / 31.0f));
  float ang = (float)s * half;
  float sn = sinf(ang), cs = cosf(ang);
  float e = v.x * cs - v.y * sn;   // even:  x[2i]c   - x[2i+1]s
  float o = v.y * cs + v.x * sn;   // odd:   x[2i+1]c + x[2i]s
  bf16 eh = f2b(e), oh = f2b(o);
  bf16 el = f2b(e - b2f(eh)), ol = f2b(o - b2f(oh));
  size_t idx = (((size_t)b * NH + h) * SEQ + s) * KD + d;  // d even -> 4B align
  bf16* ph = is_k ? kh : qh;
  bf16* pl = is_k ? kl : ql;
  union { bf16 h2[2]; unsigned u; } uh, ul;
  uh.h2[0] = eh; uh.h2[1] = oh;
  ul.h2[0] = el; ul.h2[1] = ol;
  *(unsigned*)&ph[idx] = uh.u;
  *(unsigned*)&pl[idx] = ul.u;
}

// ---------------- retention core (v3) ----------------
// grid (32, NH, B) with bt = 31-bx (heavy-first). 256 thr / 4 waves; block
// owns 64 Q-rows (wave w: rows bt*64 + w*16 ..+16). Per n-tile (32 keys):
// kh/kl/V staged once into LDS via global_load_lds (chunk-swizzled so the
// b128 fragment reads are 2-way bank-aliased = free) and shared by all 4
// waves. Uniform trip count -> __syncthreads is legal; causality via mask;
// tiles fully above a wave's rows are skipped by `active` (prefix property).
__global__ __launch_bounds__(256, 4) void retention_k(
    const bf16* __restrict__ qh, const bf16* __restrict__ ql,
    const bf16* __restrict__ kh, const bf16* __restrict__ kl,
    const bf16* __restrict__ vT, const float* __restrict__ g,
    bf16* __restrict__ gated) {
  __shared__ bf16 KHs[32 * 64];   // 4 KB  (chunk-swizzled)
  __shared__ bf16 KLs[32 * 64];   // 4 KB
  __shared__ bf16 Vs[128 * 32];   // 8 KB  (chunk-swizzled)
  __shared__ bf16 Pl[4][16 * 32]; // per-wave P round-trip, 4 KB
  const int tid = threadIdx.x;
  const int wave = tid >> 6, lane = tid & 63;
  const int quad = lane >> 4, l16 = lane & 15;
  const int h = blockIdx.y, b = blockIdx.z;
  const int bh = b * NH + h;
  const int bt = 31 - blockIdx.x;    // heavy-first
  const int m0 = bt * 64 + wave * 16;
  const int ntiles = 2 * bt + 2;

  const float t = exp2f(-(float)(5 + h));  // 1-gamma (exact)
  const float lng = log1pf(-t);            // ln(gamma)
  const float log2g = lng * 1.44269504088896340736f;

  // rf[r] = gamma^(m-n0) * inv_ms[r]; updated *gamma^-32 per tile.
  float rf[4];
#pragma unroll
  for (int r = 0; r < 4; ++r) {
    int m = m0 + quad * 4 + r;
    float num = -expm1f((float)(m + 1) * lng);  // 1-gamma^(m+1) > 0
    rf[r] = exp2f((float)m * log2g) * rsqrtf(num / t);
  }
  const float gstep = exp2f(-32.0f * log2g);      // gamma^-32
  const float cf0 = exp2f(-(float)l16 * log2g);   // gamma^-l16
  const float cf1 = cf0 * exp2f(-16.0f * log2g);  // gamma^-(16+l16)

  const size_t qoff = ((size_t)bh * SEQ + m0 + l16) * KD;
  bf16x8 aq0h = *(const bf16x8*)&qh[qoff + quad * 8];
  bf16x8 aq1h = *(const bf16x8*)&qh[qoff + 32 + quad * 8];
  bf16x8 aq0l = *(const bf16x8*)&ql[qoff + quad * 8];
  bf16x8 aq1l = *(const bf16x8*)&ql[qoff + 32 + quad * 8];

  floatx4 oacc[8] = {};
  float rowsum[4] = {0.f, 0.f, 0.f, 0.f};

  const bf16* khb = kh + (size_t)bh * SEQ * KD;
  const bf16* klb = kl + (size_t)bh * SEQ * KD;
  const bf16* vbase = vT + (size_t)bh * HD * SEQ;

  for (int nt = 0; nt < ntiles; ++nt) {
    const int n0 = nt * 32;

    // ---- stage K/V into LDS: 16 ASYNC16 calls, 4 per wave ----
    // K tiles: 32 rows x 64 elems; LDS chunk(row,s) holds global chunk
    // q=(s-row)&7  -> read with s=(q+row)&7 is 2-way bank-aliased (free).
    // V tile: 128 rows x 32 elems; chunk(row,s) holds q=(s-(row>>1))&3.
#pragma unroll
    for (int j = 0; j < 4; ++j) {
      int cc = wave * 4 + j;
      if (cc < 8) {
        const bf16* src = (cc < 4) ? khb : klb;
        bf16* dst = (cc < 4) ? KHs : KLs;
        int r = ((cc & 3) * 8) + (lane >> 3);  // row 0..31
        int s = lane & 7;
        int q = (s - r) & 7;
        const bf16* gp = src + (size_t)(n0 + r) * KD + q * 8;
        ASYNC16(gp, &dst[(cc & 3) * 512]);
      } else {
        int r = (cc - 8) * 16 + (lane >> 2);   // row 0..127
        int s = lane & 3;
        int q = (s - (r >> 1)) & 3;
        const bf16* gp = vbase + (size_t)r * SEQ + n0 + q * 8;
        ASYNC16(gp, &Vs[(cc - 8) * 512]);
      }
    }
    __syncthreads();  // vmcnt(0) drain + barrier: tile ready

    const bool active = (n0 <= m0 + 15);
    if (active) {
      // ---- QK: 3 independent chains per half, K frags from LDS ----
      floatx4 sc[2];
#pragma unroll
      for (int hh = 0; hh < 2; ++hh) {
        int krow = hh * 16 + l16;
        int c0 = ((quad + krow) & 7) * 8;
        int c1 = ((quad + 4 + krow) & 7) * 8;
        bf16x8 bkh0 = *(const bf16x8*)&KHs[krow * 64 + c0];
        bf16x8 bkh1 = *(const bf16x8*)&KHs[krow * 64 + c1];
        bf16x8 bkl0 = *(const bf16x8*)&KLs[krow * 64 + c0];
        bf16x8 bkl1 = *(const bf16x8*)&KLs[krow * 64 + c1];
        floatx4 z1 = {0.f, 0.f, 0.f, 0.f}, z2 = z1, z3 = z1;
        z1 = __builtin_amdgcn_mfma_f32_16x16x32_bf16(aq0h, bkh0, z1, 0, 0, 0);
        z2 = __builtin_amdgcn_mfma_f32_16x16x32_bf16(aq0l, bkh0, z2, 0, 0, 0);
        z3 = __builtin_amdgcn_mfma_f32_16x16x32_bf16(aq0h, bkl0, z3, 0, 0, 0);
        z1 = __builtin_amdgcn_mfma_f32_16x16x32_bf16(aq1h, bkh1, z1, 0, 0, 0);
        z2 = __builtin_amdgcn_mfma_f32_16x16x32_bf16(aq1l, bkh1, z2, 0, 0, 0);
        z3 = __builtin_amdgcn_mfma_f32_16x16x32_bf16(aq1h, bkl1, z3, 0, 0, 0);
        sc[hh] = z1 + z2 + z3;
      }

      // ---- decay mask (incremental) + row sums + stage P (per-wave) ----
#pragma unroll
      for (int hh = 0; hh < 2; ++hh) {
        float cf = hh ? cf1 : cf0;
#pragma unroll
        for (int r = 0; r < 4; ++r) {
          int m = m0 + quad * 4 + r;
          int n = n0 + hh * 16 + l16;
          float p = (m >= n) ? sc[hh][r] * rf[r] * cf : 0.f;
          rowsum[r] += p;
          Pl[wave][(quad * 4 + r) * 32 + hh * 16 + l16] = f2b(p);
        }
      }
#pragma unroll
      for (int r = 0; r < 4; ++r) rf[r] *= gstep;

      // per-wave cross-lane LDS RAW: lgkm drain + compiler barrier
      asm volatile("s_waitcnt lgkmcnt(0)" ::: "memory");
      bf16x8 pa = *(const bf16x8*)&Pl[wave][l16 * 32 + quad * 8];

      // ---- PV: V frags from LDS (swizzled) ----
#pragma unroll
      for (int dt = 0; dt < 8; ++dt) {
        int vrow = dt * 16 + l16;
        bf16x8 bv = *(const bf16x8*)&Vs[vrow * 32 + ((quad + (vrow >> 1)) & 3) * 8];
        oacc[dt] = __builtin_amdgcn_mfma_f32_16x16x32_bf16(pa, bv, oacc[dt], 0, 0, 0);
      }
    }
    __syncthreads();  // all waves done reading before next tile overwrites
  }

  // denom = clip(|row sum|, 1); groupnorm over 128 dims; silu gate
  float inv_den[4];
#pragma unroll
  for (int r = 0; r < 4; ++r) {
    float v = rowsum[r];
    v += __shfl_xor(v, 1);
    v += __shfl_xor(v, 2);
    v += __shfl_xor(v, 4);
    v += __shfl_xor(v, 8);
    inv_den[r] = 1.0f / fmaxf(fabsf(v), 1.0f);
  }
  float s1[4] = {}, s2[4] = {};
#pragma unroll
  for (int dt = 0; dt < 8; ++dt) {
#pragma unroll
    for (int r = 0; r < 4; ++r) {
      float v = oacc[dt][r] * inv_den[r];
      oacc[dt][r] = v;
      s1[r] += v;
      s2[r] += v * v;
    }
  }
  float mean[4], istd[4];
#pragma unroll
  for (int r = 0; r < 4; ++r) {
    float a = s1[r], q2 = s2[r];
    a += __shfl_xor(a, 1); a += __shfl_xor(a, 2);
    a += __shfl_xor(a, 4); a += __shfl_xor(a, 8);
    q2 += __shfl_xor(q2, 1); q2 += __shfl_xor(q2, 2);
    q2 += __shfl_xor(q2, 4); q2 += __shfl_xor(q2, 8);
    mean[r] = a * (1.0f / 128.0f);
    float var = q2 * (1.0f / 128.0f) - mean[r] * mean[r];
    istd[r] = rsqrtf(fmaxf(var, 0.0f) + 1e-5f);
  }
#pragma unroll
  for (int dt = 0; dt < 8; ++dt) {
#pragma unroll
    for (int r = 0; r < 4; ++r) {
      int m = m0 + quad * 4 + r;
      int col = h * HD + dt * 16 + l16;
      float v = (oacc[dt][r] - mean[r]) * istd[r];
      float gv = g[((size_t)b * SEQ + m) * 2048 + col];
      float sg = gv / (1.0f + expf(-gv));
      gated[((size_t)b * SEQ + m) * 2048 + col] = f2b(sg * v);
    }
  }
}

// ---------------- launch ----------------
extern "C" void kernel_launch(void* const* d_in, const int* in_sizes, int n_in,
                              void* d_out, int out_size, void* d_ws,
                              size_t ws_size, hipStream_t stream) {
  const float* x   = (const float*)d_in[0];
  const float* q_w = (const float*)d_in[1];
  const float* q_b = (const float*)d_in[2];
  const float* k_w = (const float*)d_in[3];
  const float* k_b = (const float*)d_in[4];
  const float* v_w = (const float*)d_in[5];
  const float* v_b = (const float*)d_in[6];
  const float* g_w = (const float*)d_in[7];
  const float* g_b = (const float*)d_in[8];
  const float* o_w = (const float*)d_in[9];
  const float* o_b = (const float*)d_in[10];

  char* ws = (char*)d_ws;
  bf16* Wt    = (bf16*)ws; ws += (size_t)6144 * 1024 * 2;
  bf16* oT    = (bf16*)ws; ws += (size_t)1024 * 2048 * 2;
  bf16* xb    = (bf16*)ws; ws += (size_t)4096 * 1024 * 2;
  float* Cqk  = (float*)ws; ws += (size_t)4096 * 2048 * 4;
  bf16* qhb   = (bf16*)ws; ws += (size_t)32 * 2048 * 64 * 2;
  bf16* qlb   = (bf16*)ws; ws += (size_t)32 * 2048 * 64 * 2;
  bf16* khb   = (bf16*)ws; ws += (size_t)32 * 2048 * 64 * 2;
  bf16* klb   = (bf16*)ws; ws += (size_t)32 * 2048 * 64 * 2;
  bf16* vTb   = (bf16*)ws; ws += (size_t)32 * 128 * 2048 * 2;
  float* gbuf = (float*)ws; ws += (size_t)2 * 2048 * 2048 * 4;
  bf16* gated = (bf16*)ws; ws += (size_t)4096 * 2048 * 2;

  convert_k<<<(4096 * 1024 / 4) / 256, 256, 0, stream>>>(x, xb);

  dim3 tb(32, 8);
  transpose_k<<<dim3(1024 / 32, 1024 / 32), tb, 0, stream>>>(q_w, Wt, 1024, 1024);
  transpose_k<<<dim3(1024 / 32, 1024 / 32), tb, 0, stream>>>(k_w, Wt + (size_t)1024 * 1024, 1024, 1024);
  transpose_k<<<dim3(2048 / 32, 1024 / 32), tb, 0, stream>>>(v_w, Wt + (size_t)2048 * 1024, 1024, 2048);
  transpose_k<<<dim3(2048 / 32, 1024 / 32), tb, 0, stream>>>(g_w, Wt + (size_t)4096 * 1024, 1024, 2048);
  transpose_k<<<dim3(1024 / 32, 2048 / 32), tb, 0, stream>>>(o_w, oT, 2048, 1024);

  gemm_bt<128, 128, 1024, 0><<<dim3(6144 / 128, 4096 / 128), 256, 0, stream>>>(
      xb, Wt, 6144, q_b, k_b, v_b, g_b, Cqk, vTb, gbuf, nullptr);

  router_k<<<(4096 * 1024) / 256, 256, 0, stream>>>(Cqk, qhb, qlb, khb, klb);

  retention_k<<<dim3(32, NH, B_SZ), 256, 0, stream>>>(
      qhb, qlb, khb, klb, vTb, gbuf, gated);

  gemm_bt<128, 64, 2048, 1><<<dim3(1024 / 64, 4096 / 128), 256, 0, stream>>>(
      gated, oT, 1024, o_b, nullptr, nullptr, nullptr, nullptr, nullptr,
      nullptr, (float*)d_out);
}

// Round 9
// 372.210 us; speedup vs baseline: 2.0694x; 1.0193x over previous
//
#include <hip/hip_runtime.h>
#include <hip/hip_bf16.h>

// MultiScaleRetention forward. Inputs/outputs FLOAT32; internals bf16 MFMA.
//   0) convert x -> xb (bf16); transpose weights f32 -> bf16
//   1) GEMM1 (m97-style, global_load_lds staging): xb @ Wt^T; LEAN epilogue,
//      ALL-COALESCED: qk -> f32 Cqk (+bias,+k-scale); v -> bf16 vbuf
//      (natural layout); g -> f32
//   2) vtrans: vbuf (b, s, 2048) -> vT (bh, 128, S)  [LDS-tiled]
//   3) router: rotary (f32) + hi/lo bf16 split + (bh,S,64) layout for q,k
//   4) retention: 4-wave blocks, DOUBLE-BUFFERED K/V LDS staging,
//      split-precision QK^T -> decay-mask -> PV; groupnorm+silu fused
//   5) GEMM2: gated @ oT^T + o_b -> d_out (f32)
//
// R9 changes vs R8 (tripwire: graph replay diverged from launch_once =
// timing-dependent race; only R8 change w/ new sync semantics was the
// retention double-buffer; its correctness relied on the compiler emitting
// vmcnt(0) before s_barrier for DMAs issued on a CONDITIONAL path across the
// loop back-edge — DMA loads have no dest VGPR, so no register-use wait
// backstops a dropped barrier wait):
//   - explicit s_waitcnt vmcnt(0) lgkmcnt(0) before the top-of-loop barrier
//     (drains prefetch issued a full compute phase ago; overlap preserved)
//   - prefetch made unconditional (pf clamped; last iter re-stages current
//     tile into the dead buffer) -> uniform pending-counter state at barrier
// Math bit-identical to R7/R8 -> absmax must stay 0.01049805.

typedef __hip_bfloat16 bf16;
typedef short bf16x4 __attribute__((ext_vector_type(4)));
typedef short bf16x8 __attribute__((ext_vector_type(8)));
typedef float floatx4 __attribute__((ext_vector_type(4)));

#define B_SZ 2
#define SEQ 2048
#define NH 16
#define KD 64
#define HD 128

// global->LDS direct copy, 16B/lane. LDS dest is wave-uniform base + lane*16.
#define ASYNC16(gp, lp)                                                             \
  __builtin_amdgcn_global_load_lds(                                                 \
      (const __attribute__((address_space(1))) unsigned int*)(unsigned long long)(const void*)(gp), \
      (__attribute__((address_space(3))) unsigned int*)(unsigned int)(unsigned long long)(void*)(lp), \
      16, 0, 0)

__device__ __forceinline__ float b2f(bf16 x) { return __bfloat162float(x); }
__device__ __forceinline__ bf16 f2b(float x) { return __float2bfloat16(x); }

// ---------------- f32 -> bf16 convert (x) ----------------
__global__ void convert_k(const float* __restrict__ in, bf16* __restrict__ out) {
  int i = blockIdx.x * 256 + threadIdx.x;  // one float4 per thread
  float4 v = reinterpret_cast<const float4*>(in)[i];
  union { bf16 h[4]; bf16x4 v4; } u;
  u.h[0] = f2b(v.x); u.h[1] = f2b(v.y); u.h[2] = f2b(v.z); u.h[3] = f2b(v.w);
  reinterpret_cast<bf16x4*>(out)[i] = u.v4;
}

// ---------------- weight transpose: in f32 (K,N) -> out bf16 (N,K) --------
__global__ void transpose_k(const float* __restrict__ in, bf16* __restrict__ out,
                            int K, int N) {
  __shared__ float tile[32][33];
  int tx = threadIdx.x, ty = threadIdx.y;
  int n0 = blockIdx.x * 32, k0 = blockIdx.y * 32;
#pragma unroll
  for (int j = 0; j < 4; ++j)
    tile[ty + j * 8][tx] = in[(size_t)(k0 + ty + j * 8) * N + n0 + tx];
  __syncthreads();
#pragma unroll
  for (int j = 0; j < 4; ++j)
    out[(size_t)(n0 + ty + j * 8) * K + k0 + tx] = f2b(tile[tx][ty + j * 8]);
}

// ---------------- v transpose: per-b 2048x2048 bf16 ----------------
// vbuf (b, s, c) -> vT (b, c, s)   [c = h*128+d; vT flat = (b*2048+c)*SEQ+s]
__global__ void vtrans_k(const bf16* __restrict__ in, bf16* __restrict__ out) {
  __shared__ bf16 tile[32][34];  // +2 pad
  int tx = threadIdx.x, ty = threadIdx.y;
  int s0 = blockIdx.x * 32, c0 = blockIdx.y * 32;
  const bf16* src = in + (size_t)blockIdx.z * 2048 * 2048;
  bf16* dst = out + (size_t)blockIdx.z * 2048 * 2048;
#pragma unroll
  for (int j = 0; j < 4; ++j)
    tile[ty + j * 8][tx] = src[(size_t)(s0 + ty + j * 8) * 2048 + c0 + tx];
  __syncthreads();
#pragma unroll
  for (int j = 0; j < 4; ++j)
    dst[(size_t)(c0 + ty + j * 8) * 2048 + s0 + tx] = tile[tx][ty + j * 8];
}

// ---------------- GEMM: C(M,N) = A(M,K) @ Bt(N,K)^T ----------------
// MODE 0: QKVG epilogue (bias; qk -> f32 Cqk; v -> bf16 vbuf; g -> f32)
// MODE 1: output projection epilogue (f32 bias + f32 store)
template <int BM, int BN, int KDIM, int MODE>
__global__ __launch_bounds__(256, 2) void gemm_bt(
    const bf16* __restrict__ A, const bf16* __restrict__ Bt, int Ndim,
    const float* __restrict__ bias_q, const float* __restrict__ bias_k,
    const float* __restrict__ bias_v, const float* __restrict__ bias_g,
    float* __restrict__ outCqk, bf16* __restrict__ out_v,
    float* __restrict__ out_g, float* __restrict__ outF) {
  __shared__ bf16 As[BM * 32];
  __shared__ bf16 Bs[BN * 32];
  const int tid = threadIdx.x;
  const int wave = tid >> 6, lane = tid & 63;
  const int quad = lane >> 4, l16 = lane & 15;
  const int m0 = blockIdx.y * BM, n0 = blockIdx.x * BN;
  constexpr int FI = BM / 32;
  constexpr int FJ = BN / 32;
  const int wm = (wave >> 1) * (BM / 2), wn = (wave & 1) * (BN / 2);

  floatx4 acc[FI][FJ] = {};

  for (int k0 = 0; k0 < KDIM; k0 += 32) {
#pragma unroll
    for (int j = 0; j < BM / 64; ++j) {
      int cbase = (j * 4 + wave) * 64;
      int c = cbase + lane;
      const bf16* g = A + (size_t)(m0 + (c >> 2)) * KDIM + k0 + (c & 3) * 8;
      ASYNC16(g, &As[cbase * 8]);
    }
#pragma unroll
    for (int j = 0; j < BN / 64; ++j) {
      int cbase = (j * 4 + wave) * 64;
      int c = cbase + lane;
      const bf16* g = Bt + (size_t)(n0 + (c >> 2)) * KDIM + k0 + (c & 3) * 8;
      ASYNC16(g, &Bs[cbase * 8]);
    }
    __syncthreads();  // compiler drains vmcnt(0) before s_barrier

    bf16x8 af[FI], bfr[FJ];
#pragma unroll
    for (int i = 0; i < FI; ++i)
      af[i] = *(const bf16x8*)&As[(wm + i * 16 + l16) * 32 + quad * 8];
#pragma unroll
    for (int j = 0; j < FJ; ++j)
      bfr[j] = *(const bf16x8*)&Bs[(wn + j * 16 + l16) * 32 + quad * 8];
#pragma unroll
    for (int i = 0; i < FI; ++i)
#pragma unroll
      for (int j = 0; j < FJ; ++j)
        acc[i][j] = __builtin_amdgcn_mfma_f32_16x16x32_bf16(af[i], bfr[j],
                                                            acc[i][j], 0, 0, 0);
    __syncthreads();
  }

  // LEAN epilogue, all stores coalesced: col=lane&15 (n), row=quad*4+r (m)
#pragma unroll
  for (int i = 0; i < FI; ++i) {
#pragma unroll
    for (int j = 0; j < FJ; ++j) {
#pragma unroll
      for (int r = 0; r < 4; ++r) {
        int gm = m0 + wm + i * 16 + quad * 4 + r;
        int gn = n0 + wn + j * 16 + l16;
        float v = acc[i][j][r];
        if (MODE == 1) {
          v += bias_q[gn];  // bias_q = o_b
          outF[(size_t)gm * Ndim + gn] = v;
        } else {
          if (gn < 2048) {
            bool is_k = gn >= 1024;
            int jj = is_k ? gn - 1024 : gn;
            v += is_k ? bias_k[jj] : bias_q[jj];
            if (is_k) v *= 0.125f;  // SCALING = KEY_DIM^-0.5
            outCqk[(size_t)gm * 2048 + gn] = v;  // f32, exact
          } else if (gn < 4096) {
            int jj = gn - 2048;
            v += bias_v[jj];
            out_v[(size_t)gm * 2048 + jj] = f2b(v);  // natural layout
          } else {
            int jj = gn - 4096;
            v += bias_g[jj];
            out_g[(size_t)gm * 2048 + jj] = v;  // f32
          }
        }
      }
    }
  }
}

// ---------------- router: rotary + hi/lo split + layout ----------------
// one thread per rotary pair; Cqk (4096, 2048) f32: cols 0..1023 q, 1024.. k
__global__ void router_k(const float* __restrict__ Cqk,
                         bf16* __restrict__ qh, bf16* __restrict__ ql,
                         bf16* __restrict__ kh, bf16* __restrict__ kl) {
  int t = blockIdx.x * 256 + threadIdx.x;  // 4096*1024 threads
  int row = t >> 10, pc = t & 1023;
  int b = row >> 11, s = row & 2047;
  bool is_k = pc >= 512;
  int jj = (pc - (is_k ? 512 : 0)) * 2;  // even, 0..1022
  int h = jj >> 6, d = jj & 63, ii = d >> 1;
  float2 v = *(const float2*)&Cqk[(size_t)row * 2048 + pc * 2];
  // half[ii] = 10000^(-ii/31); ang = s * half[ii]
  float half = exp2f(-(float)ii * (13.287712379549449f / 31.0f));
  float ang = (float)s * half;
  float sn = sinf(ang), cs = cosf(ang);
  float e = v.x * cs - v.y * sn;   // even:  x[2i]c   - x[2i+1]s
  float o = v.y * cs + v.x * sn;   // odd:   x[2i+1]c + x[2i]s
  bf16 eh = f2b(e), oh = f2b(o);
  bf16 el = f2b(e - b2f(eh)), ol = f2b(o - b2f(oh));
  size_t idx = (((size_t)b * NH + h) * SEQ + s) * KD + d;  // d even -> 4B align
  bf16* ph = is_k ? kh : qh;
  bf16* pl = is_k ? kl : ql;
  union { bf16 h2[2]; unsigned u; } uh, ul;
  uh.h2[0] = eh; uh.h2[1] = oh;
  ul.h2[0] = el; ul.h2[1] = ol;
  *(unsigned*)&ph[idx] = uh.u;
  *(unsigned*)&pl[idx] = ul.u;
}

// ---------------- retention core (v5: hardened double-buffer) ------------
// grid (32, NH, B), bt = 31-bx (heavy-first). 256 thr / 4 waves; block owns
// 64 Q-rows. K(hi/lo)/V per 32-key n-tile staged once into ping-pong LDS via
// global_load_lds, shared by all 4 waves. One barrier per tile; the EXPLICIT
// vmcnt drain before it guarantees the previous iteration's prefetch landed
// (compiler's implicit barrier-drain is not trusted for dest-register-less
// DMA issued across the back-edge — R8 tripwire).
__global__ __launch_bounds__(256, 4) void retention_k(
    const bf16* __restrict__ qh, const bf16* __restrict__ ql,
    const bf16* __restrict__ kh, const bf16* __restrict__ kl,
    const bf16* __restrict__ vT, const float* __restrict__ g,
    bf16* __restrict__ gated) {
  __shared__ bf16 KHs[2][32 * 64];   // 2 x 4 KB (chunk-swizzled)
  __shared__ bf16 KLs[2][32 * 64];   // 2 x 4 KB
  __shared__ bf16 Vs[2][128 * 32];   // 2 x 8 KB (chunk-swizzled)
  __shared__ bf16 Pl[4][16 * 32];    // per-wave P round-trip, 4 KB
  const int tid = threadIdx.x;
  const int wave = tid >> 6, lane = tid & 63;
  const int quad = lane >> 4, l16 = lane & 15;
  const int h = blockIdx.y, b = blockIdx.z;
  const int bh = b * NH + h;
  const int bt = 31 - blockIdx.x;    // heavy-first
  const int m0 = bt * 64 + wave * 16;
  const int ntiles = 2 * bt + 2;

  const float t = exp2f(-(float)(5 + h));  // 1-gamma (exact)
  const float lng = log1pf(-t);            // ln(gamma)
  const float log2g = lng * 1.44269504088896340736f;

  // rf[r] = gamma^(m-n0) * inv_ms[r]; updated *gamma^-32 per tile.
  float rf[4];
#pragma unroll
  for (int r = 0; r < 4; ++r) {
    int m = m0 + quad * 4 + r;
    float num = -expm1f((float)(m + 1) * lng);  // 1-gamma^(m+1) > 0
    rf[r] = exp2f((float)m * log2g) * rsqrtf(num / t);
  }
  const float gstep = exp2f(-32.0f * log2g);      // gamma^-32
  const float cf0 = exp2f(-(float)l16 * log2g);   // gamma^-l16
  const float cf1 = cf0 * exp2f(-16.0f * log2g);  // gamma^-(16+l16)

  const size_t qoff = ((size_t)bh * SEQ + m0 + l16) * KD;
  bf16x8 aq0h = *(const bf16x8*)&qh[qoff + quad * 8];
  bf16x8 aq1h = *(const bf16x8*)&qh[qoff + 32 + quad * 8];
  bf16x8 aq0l = *(const bf16x8*)&ql[qoff + quad * 8];
  bf16x8 aq1l = *(const bf16x8*)&ql[qoff + 32 + quad * 8];

  floatx4 oacc[8] = {};
  float rowsum[4] = {0.f, 0.f, 0.f, 0.f};

  const bf16* khb = kh + (size_t)bh * SEQ * KD;
  const bf16* klb = kl + (size_t)bh * SEQ * KD;
  const bf16* vbase = vT + (size_t)bh * HD * SEQ;

  // stage tile nt into buffer buf: 16 ASYNC16, 4 per wave (waves 0,1: K; 2,3: V)
  auto stage = [&](int nt, int buf) {
    const int n0s = nt * 32;
#pragma unroll
    for (int j = 0; j < 4; ++j) {
      int cc = wave * 4 + j;
      if (cc < 8) {
        const bf16* src = (cc < 4) ? khb : klb;
        bf16* dst = (cc < 4) ? KHs[buf] : KLs[buf];
        int r = ((cc & 3) * 8) + (lane >> 3);  // row 0..31
        int s = lane & 7;
        int q = (s - r) & 7;
        ASYNC16(src + (size_t)(n0s + r) * KD + q * 8, &dst[(cc & 3) * 512]);
      } else {
        int r = (cc - 8) * 16 + (lane >> 2);   // row 0..127
        int s = lane & 3;
        int q = (s - (r >> 1)) & 3;
        ASYNC16(vbase + (size_t)r * SEQ + n0s + q * 8, &Vs[buf][(cc - 8) * 512]);
      }
    }
  };

  stage(0, 0);
  for (int nt = 0; nt < ntiles; ++nt) {
    const int n0 = nt * 32;
    const int cur = nt & 1;
    // EXPLICIT drain of the prefetch issued a full compute phase ago, then
    // barrier (RAW: this tile's DMA visible to all; WAR: all waves done
    // reading the buffer the next prefetch will overwrite).
    asm volatile("s_waitcnt vmcnt(0) lgkmcnt(0)" ::: "memory");
    __syncthreads();
    {  // unconditional prefetch: uniform counter state across the back-edge
      int pf = (nt + 1 < ntiles) ? nt + 1 : nt;
      stage(pf, cur ^ 1);
    }

    const bool active = (n0 <= m0 + 15);
    if (active) {
      // ---- QK: 3 independent chains per half, K frags from LDS ----
      floatx4 sc[2];
#pragma unroll
      for (int hh = 0; hh < 2; ++hh) {
        int krow = hh * 16 + l16;
        int c0 = ((quad + krow) & 7) * 8;
        int c1 = ((quad + 4 + krow) & 7) * 8;
        bf16x8 bkh0 = *(const bf16x8*)&KHs[cur][krow * 64 + c0];
        bf16x8 bkh1 = *(const bf16x8*)&KHs[cur][krow * 64 + c1];
        bf16x8 bkl0 = *(const bf16x8*)&KLs[cur][krow * 64 + c0];
        bf16x8 bkl1 = *(const bf16x8*)&KLs[cur][krow * 64 + c1];
        floatx4 z1 = {0.f, 0.f, 0.f, 0.f}, z2 = z1, z3 = z1;
        z1 = __builtin_amdgcn_mfma_f32_16x16x32_bf16(aq0h, bkh0, z1, 0, 0, 0);
        z2 = __builtin_amdgcn_mfma_f32_16x16x32_bf16(aq0l, bkh0, z2, 0, 0, 0);
        z3 = __builtin_amdgcn_mfma_f32_16x16x32_bf16(aq0h, bkl0, z3, 0, 0, 0);
        z1 = __builtin_amdgcn_mfma_f32_16x16x32_bf16(aq1h, bkh1, z1, 0, 0, 0);
        z2 = __builtin_amdgcn_mfma_f32_16x16x32_bf16(aq1l, bkh1, z2, 0, 0, 0);
        z3 = __builtin_amdgcn_mfma_f32_16x16x32_bf16(aq1h, bkl1, z3, 0, 0, 0);
        sc[hh] = z1 + z2 + z3;
      }

      // ---- decay mask (incremental) + row sums + stage P (per-wave) ----
#pragma unroll
      for (int hh = 0; hh < 2; ++hh) {
        float cf = hh ? cf1 : cf0;
#pragma unroll
        for (int r = 0; r < 4; ++r) {
          int m = m0 + quad * 4 + r;
          int n = n0 + hh * 16 + l16;
          float p = (m >= n) ? sc[hh][r] * rf[r] * cf : 0.f;
          rowsum[r] += p;
          Pl[wave][(quad * 4 + r) * 32 + hh * 16 + l16] = f2b(p);
        }
      }
#pragma unroll
      for (int r = 0; r < 4; ++r) rf[r] *= gstep;

      // per-wave cross-lane LDS RAW: lgkm drain + compiler barrier
      asm volatile("s_waitcnt lgkmcnt(0)" ::: "memory");
      bf16x8 pa = *(const bf16x8*)&Pl[wave][l16 * 32 + quad * 8];

      // ---- PV: V frags from LDS (swizzled) ----
#pragma unroll
      for (int dt = 0; dt < 8; ++dt) {
        int vrow = dt * 16 + l16;
        bf16x8 bv = *(const bf16x8*)&Vs[cur][vrow * 32 + ((quad + (vrow >> 1)) & 3) * 8];
        oacc[dt] = __builtin_amdgcn_mfma_f32_16x16x32_bf16(pa, bv, oacc[dt], 0, 0, 0);
      }
    }
  }

  // denom = clip(|row sum|, 1); groupnorm over 128 dims; silu gate
  float inv_den[4];
#pragma unroll
  for (int r = 0; r < 4; ++r) {
    float v = rowsum[r];
    v += __shfl_xor(v, 1);
    v += __shfl_xor(v, 2);
    v += __shfl_xor(v, 4);
    v += __shfl_xor(v, 8);
    inv_den[r] = 1.0f / fmaxf(fabsf(v), 1.0f);
  }
  float s1[4] = {}, s2[4] = {};
#pragma unroll
  for (int dt = 0; dt < 8; ++dt) {
#pragma unroll
    for (int r = 0; r < 4; ++r) {
      float v = oacc[dt][r] * inv_den[r];
      oacc[dt][r] = v;
      s1[r] += v;
      s2[r] += v * v;
    }
  }
  float mean[4], istd[4];
#pragma unroll
  for (int r = 0; r < 4; ++r) {
    float a = s1[r], q2 = s2[r];
    a += __shfl_xor(a, 1); a += __shfl_xor(a, 2);
    a += __shfl_xor(a, 4); a += __shfl_xor(a, 8);
    q2 += __shfl_xor(q2, 1); q2 += __shfl_xor(q2, 2);
    q2 += __shfl_xor(q2, 4); q2 += __shfl_xor(q2, 8);
    mean[r] = a * (1.0f / 128.0f);
    float var = q2 * (1.0f / 128.0f) - mean[r] * mean[r];
    istd[r] = rsqrtf(fmaxf(var, 0.0f) + 1e-5f);
  }
#pragma unroll
  for (int dt = 0; dt < 8; ++dt) {
#pragma unroll
    for (int r = 0; r < 4; ++r) {
      int m = m0 + quad * 4 + r;
      int col = h * HD + dt * 16 + l16;
      float v = (oacc[dt][r] - mean[r]) * istd[r];
      float gv = g[((size_t)b * SEQ + m) * 2048 + col];
      float sg = gv / (1.0f + expf(-gv));
      gated[((size_t)b * SEQ + m) * 2048 + col] = f2b(sg * v);
    }
  }
}

// ---------------- launch ----------------
extern "C" void kernel_launch(void* const* d_in, const int* in_sizes, int n_in,
                              void* d_out, int out_size, void* d_ws,
                              size_t ws_size, hipStream_t stream) {
  const float* x   = (const float*)d_in[0];
  const float* q_w = (const float*)d_in[1];
  const float* q_b = (const float*)d_in[2];
  const float* k_w = (const float*)d_in[3];
  const float* k_b = (const float*)d_in[4];
  const float* v_w = (const float*)d_in[5];
  const float* v_b = (const float*)d_in[6];
  const float* g_w = (const float*)d_in[7];
  const float* g_b = (const float*)d_in[8];
  const float* o_w = (const float*)d_in[9];
  const float* o_b = (const float*)d_in[10];

  char* ws = (char*)d_ws;
  bf16* Wt    = (bf16*)ws; ws += (size_t)6144 * 1024 * 2;
  bf16* oT    = (bf16*)ws; ws += (size_t)1024 * 2048 * 2;
  bf16* xb    = (bf16*)ws; ws += (size_t)4096 * 1024 * 2;
  float* Cqk  = (float*)ws; ws += (size_t)4096 * 2048 * 4;
  bf16* qhb   = (bf16*)ws; ws += (size_t)32 * 2048 * 64 * 2;
  bf16* qlb   = (bf16*)ws; ws += (size_t)32 * 2048 * 64 * 2;
  bf16* khb   = (bf16*)ws; ws += (size_t)32 * 2048 * 64 * 2;
  bf16* klb   = (bf16*)ws; ws += (size_t)32 * 2048 * 64 * 2;
  bf16* vTb   = (bf16*)ws; ws += (size_t)32 * 128 * 2048 * 2;
  float* gbuf = (float*)ws; ws += (size_t)2 * 2048 * 2048 * 4;
  bf16* gated = (bf16*)ws; ws += (size_t)4096 * 2048 * 2;
  // vbuf aliases gated: vbuf lives GEMM1->vtrans, gated lives retention->GEMM2
  bf16* vbuf  = gated;

  convert_k<<<(4096 * 1024 / 4) / 256, 256, 0, stream>>>(x, xb);

  dim3 tb(32, 8);
  transpose_k<<<dim3(1024 / 32, 1024 / 32), tb, 0, stream>>>(q_w, Wt, 1024, 1024);
  transpose_k<<<dim3(1024 / 32, 1024 / 32), tb, 0, stream>>>(k_w, Wt + (size_t)1024 * 1024, 1024, 1024);
  transpose_k<<<dim3(2048 / 32, 1024 / 32), tb, 0, stream>>>(v_w, Wt + (size_t)2048 * 1024, 1024, 2048);
  transpose_k<<<dim3(2048 / 32, 1024 / 32), tb, 0, stream>>>(g_w, Wt + (size_t)4096 * 1024, 1024, 2048);
  transpose_k<<<dim3(1024 / 32, 2048 / 32), tb, 0, stream>>>(o_w, oT, 2048, 1024);

  gemm_bt<128, 128, 1024, 0><<<dim3(6144 / 128, 4096 / 128), 256, 0, stream>>>(
      xb, Wt, 6144, q_b, k_b, v_b, g_b, Cqk, vbuf, gbuf, nullptr);

  vtrans_k<<<dim3(64, 64, B_SZ), tb, 0, stream>>>(vbuf, vTb);

  router_k<<<(4096 * 1024) / 256, 256, 0, stream>>>(Cqk, qhb, qlb, khb, klb);

  retention_k<<<dim3(32, NH, B_SZ), 256, 0, stream>>>(
      qhb, qlb, khb, klb, vTb, gbuf, gated);

  gemm_bt<128, 64, 2048, 1><<<dim3(1024 / 64, 4096 / 128), 256, 0, stream>>>(
      gated, oT, 1024, o_b, nullptr, nullptr, nullptr, nullptr, nullptr,
      nullptr, (float*)d_out);
}

// Round 10
// 356.440 us; speedup vs baseline: 2.1609x; 1.0442x over previous
//
#include <hip/hip_runtime.h>
#include <hip/hip_bf16.h>

// MultiScaleRetention forward. Inputs/outputs FLOAT32; internals bf16 MFMA.
//   0) convert x -> xb (bf16); transpose weights f32 -> bf16
//   1) GEMM1 (m97-style, global_load_lds staging): xb @ Wt^T; LEAN epilogue,
//      ALL-COALESCED: qk -> f32 Cqk (+bias,+k-scale); v -> bf16 vbuf; g -> f32
//   2) vtrans: vbuf (b, s, 2048) -> vT (bh, 128, S)
//   3) router: rotary (f32) + hi/lo bf16 split + (bh,S,64) layout for q,k
//   4) retention: PAIRED m-stripes (bt, 31-bt) per block -> uniform 66
//      tile-computes/block; shared K/V LDS tile AND shared K/V register
//      fragments between the two stripes; double-buffered staging
//   5) GEMM2: gated @ oT^T + o_b -> d_out (f32)
//
// R10 changes vs R9 (retention 126us unchanged by dbuf; real culprit: grid
// 1024 blocks = whole grid co-resident, so per-block work imbalance (2..64
// tiles) directly sets the critical path — OccupancyPercent 20.7% is idle
// slots from retired light blocks):
//   - triangle pairing: grid (16,NH,B); block bx computes stripes 31-bx
//     (heavy) and bx (light) in ONE n-tile loop; light stripe reuses the
//     K/V fragments already in registers -> uniform work, LDS reads/tile
//     unchanged, MFMA/staged-byte doubled
// Per-stripe math bit-identical to R9 -> absmax must stay 0.01049805.

typedef __hip_bfloat16 bf16;
typedef short bf16x4 __attribute__((ext_vector_type(4)));
typedef short bf16x8 __attribute__((ext_vector_type(8)));
typedef float floatx4 __attribute__((ext_vector_type(4)));

#define B_SZ 2
#define SEQ 2048
#define NH 16
#define KD 64
#define HD 128

// global->LDS direct copy, 16B/lane. LDS dest is wave-uniform base + lane*16.
#define ASYNC16(gp, lp)                                                             \
  __builtin_amdgcn_global_load_lds(                                                 \
      (const __attribute__((address_space(1))) unsigned int*)(unsigned long long)(const void*)(gp), \
      (__attribute__((address_space(3))) unsigned int*)(unsigned int)(unsigned long long)(void*)(lp), \
      16, 0, 0)

__device__ __forceinline__ float b2f(bf16 x) { return __bfloat162float(x); }
__device__ __forceinline__ bf16 f2b(float x) { return __float2bfloat16(x); }

// ---------------- f32 -> bf16 convert (x) ----------------
__global__ void convert_k(const float* __restrict__ in, bf16* __restrict__ out) {
  int i = blockIdx.x * 256 + threadIdx.x;  // one float4 per thread
  float4 v = reinterpret_cast<const float4*>(in)[i];
  union { bf16 h[4]; bf16x4 v4; } u;
  u.h[0] = f2b(v.x); u.h[1] = f2b(v.y); u.h[2] = f2b(v.z); u.h[3] = f2b(v.w);
  reinterpret_cast<bf16x4*>(out)[i] = u.v4;
}

// ---------------- weight transpose: in f32 (K,N) -> out bf16 (N,K) --------
__global__ void transpose_k(const float* __restrict__ in, bf16* __restrict__ out,
                            int K, int N) {
  __shared__ float tile[32][33];
  int tx = threadIdx.x, ty = threadIdx.y;
  int n0 = blockIdx.x * 32, k0 = blockIdx.y * 32;
#pragma unroll
  for (int j = 0; j < 4; ++j)
    tile[ty + j * 8][tx] = in[(size_t)(k0 + ty + j * 8) * N + n0 + tx];
  __syncthreads();
#pragma unroll
  for (int j = 0; j < 4; ++j)
    out[(size_t)(n0 + ty + j * 8) * K + k0 + tx] = f2b(tile[tx][ty + j * 8]);
}

// ---------------- v transpose: per-b 2048x2048 bf16 ----------------
__global__ void vtrans_k(const bf16* __restrict__ in, bf16* __restrict__ out) {
  __shared__ bf16 tile[32][34];
  int tx = threadIdx.x, ty = threadIdx.y;
  int s0 = blockIdx.x * 32, c0 = blockIdx.y * 32;
  const bf16* src = in + (size_t)blockIdx.z * 2048 * 2048;
  bf16* dst = out + (size_t)blockIdx.z * 2048 * 2048;
#pragma unroll
  for (int j = 0; j < 4; ++j)
    tile[ty + j * 8][tx] = src[(size_t)(s0 + ty + j * 8) * 2048 + c0 + tx];
  __syncthreads();
#pragma unroll
  for (int j = 0; j < 4; ++j)
    dst[(size_t)(c0 + ty + j * 8) * 2048 + s0 + tx] = tile[tx][ty + j * 8];
}

// ---------------- GEMM: C(M,N) = A(M,K) @ Bt(N,K)^T ----------------
template <int BM, int BN, int KDIM, int MODE>
__global__ __launch_bounds__(256, 2) void gemm_bt(
    const bf16* __restrict__ A, const bf16* __restrict__ Bt, int Ndim,
    const float* __restrict__ bias_q, const float* __restrict__ bias_k,
    const float* __restrict__ bias_v, const float* __restrict__ bias_g,
    float* __restrict__ outCqk, bf16* __restrict__ out_v,
    float* __restrict__ out_g, float* __restrict__ outF) {
  __shared__ bf16 As[BM * 32];
  __shared__ bf16 Bs[BN * 32];
  const int tid = threadIdx.x;
  const int wave = tid >> 6, lane = tid & 63;
  const int quad = lane >> 4, l16 = lane & 15;
  const int m0 = blockIdx.y * BM, n0 = blockIdx.x * BN;
  constexpr int FI = BM / 32;
  constexpr int FJ = BN / 32;
  const int wm = (wave >> 1) * (BM / 2), wn = (wave & 1) * (BN / 2);

  floatx4 acc[FI][FJ] = {};

  for (int k0 = 0; k0 < KDIM; k0 += 32) {
#pragma unroll
    for (int j = 0; j < BM / 64; ++j) {
      int cbase = (j * 4 + wave) * 64;
      int c = cbase + lane;
      const bf16* g = A + (size_t)(m0 + (c >> 2)) * KDIM + k0 + (c & 3) * 8;
      ASYNC16(g, &As[cbase * 8]);
    }
#pragma unroll
    for (int j = 0; j < BN / 64; ++j) {
      int cbase = (j * 4 + wave) * 64;
      int c = cbase + lane;
      const bf16* g = Bt + (size_t)(n0 + (c >> 2)) * KDIM + k0 + (c & 3) * 8;
      ASYNC16(g, &Bs[cbase * 8]);
    }
    __syncthreads();  // compiler drains vmcnt(0) before s_barrier

    bf16x8 af[FI], bfr[FJ];
#pragma unroll
    for (int i = 0; i < FI; ++i)
      af[i] = *(const bf16x8*)&As[(wm + i * 16 + l16) * 32 + quad * 8];
#pragma unroll
    for (int j = 0; j < FJ; ++j)
      bfr[j] = *(const bf16x8*)&Bs[(wn + j * 16 + l16) * 32 + quad * 8];
#pragma unroll
    for (int i = 0; i < FI; ++i)
#pragma unroll
      for (int j = 0; j < FJ; ++j)
        acc[i][j] = __builtin_amdgcn_mfma_f32_16x16x32_bf16(af[i], bfr[j],
                                                            acc[i][j], 0, 0, 0);
    __syncthreads();
  }

  // LEAN epilogue, all stores coalesced
#pragma unroll
  for (int i = 0; i < FI; ++i) {
#pragma unroll
    for (int j = 0; j < FJ; ++j) {
#pragma unroll
      for (int r = 0; r < 4; ++r) {
        int gm = m0 + wm + i * 16 + quad * 4 + r;
        int gn = n0 + wn + j * 16 + l16;
        float v = acc[i][j][r];
        if (MODE == 1) {
          v += bias_q[gn];  // bias_q = o_b
          outF[(size_t)gm * Ndim + gn] = v;
        } else {
          if (gn < 2048) {
            bool is_k = gn >= 1024;
            int jj = is_k ? gn - 1024 : gn;
            v += is_k ? bias_k[jj] : bias_q[jj];
            if (is_k) v *= 0.125f;  // SCALING = KEY_DIM^-0.5
            outCqk[(size_t)gm * 2048 + gn] = v;  // f32, exact
          } else if (gn < 4096) {
            int jj = gn - 2048;
            v += bias_v[jj];
            out_v[(size_t)gm * 2048 + jj] = f2b(v);  // natural layout
          } else {
            int jj = gn - 4096;
            v += bias_g[jj];
            out_g[(size_t)gm * 2048 + jj] = v;  // f32
          }
        }
      }
    }
  }
}

// ---------------- router: rotary + hi/lo split + layout ----------------
__global__ void router_k(const float* __restrict__ Cqk,
                         bf16* __restrict__ qh, bf16* __restrict__ ql,
                         bf16* __restrict__ kh, bf16* __restrict__ kl) {
  int t = blockIdx.x * 256 + threadIdx.x;  // 4096*1024 threads
  int row = t >> 10, pc = t & 1023;
  int b = row >> 11, s = row & 2047;
  bool is_k = pc >= 512;
  int jj = (pc - (is_k ? 512 : 0)) * 2;  // even, 0..1022
  int h = jj >> 6, d = jj & 63, ii = d >> 1;
  float2 v = *(const float2*)&Cqk[(size_t)row * 2048 + pc * 2];
  float half = exp2f(-(float)ii * (13.287712379549449f / 31.0f));
  float ang = (float)s * half;
  float sn = sinf(ang), cs = cosf(ang);
  float e = v.x * cs - v.y * sn;
  float o = v.y * cs + v.x * sn;
  bf16 eh = f2b(e), oh = f2b(o);
  bf16 el = f2b(e - b2f(eh)), ol = f2b(o - b2f(oh));
  size_t idx = (((size_t)b * NH + h) * SEQ + s) * KD + d;
  bf16* ph = is_k ? kh : qh;
  bf16* pl = is_k ? kl : ql;
  union { bf16 h2[2]; unsigned u; } uh, ul;
  uh.h2[0] = eh; uh.h2[1] = oh;
  ul.h2[0] = el; ul.h2[1] = ol;
  *(unsigned*)&ph[idx] = uh.u;
  *(unsigned*)&pl[idx] = ul.u;
}

// ---------------- retention core (v6: paired stripes) ----------------
// grid (16, NH, B). Block bx owns TWO 64-row m-stripes: heavy bt_h=31-bx and
// light bt_l=bx -> uniform 66 tile-computes per block (512 blocks = 2/CU,
// uniformly busy). One n-tile loop over the heavy range; light stripe
// computed while in its own (prefix) range, REUSING the K/V register
// fragments of the heavy stripe. Double-buffered LDS staging with explicit
// vmcnt drain (R9 hardening). Per-stripe math identical to R9.
__global__ __launch_bounds__(256, 2) void retention_k(
    const bf16* __restrict__ qh, const bf16* __restrict__ ql,
    const bf16* __restrict__ kh, const bf16* __restrict__ kl,
    const bf16* __restrict__ vT, const float* __restrict__ g,
    bf16* __restrict__ gated) {
  __shared__ bf16 KHs[2][32 * 64];
  __shared__ bf16 KLs[2][32 * 64];
  __shared__ bf16 Vs[2][128 * 32];
  __shared__ bf16 Plh[4][16 * 32];
  __shared__ bf16 Pll[4][16 * 32];
  const int tid = threadIdx.x;
  const int wave = tid >> 6, lane = tid & 63;
  const int quad = lane >> 4, l16 = lane & 15;
  const int h = blockIdx.y, b = blockIdx.z;
  const int bh = b * NH + h;
  const int bt_h = 31 - (int)blockIdx.x;  // heavy stripe
  const int bt_l = (int)blockIdx.x;       // light stripe
  const int m0h = bt_h * 64 + wave * 16;
  const int m0l = bt_l * 64 + wave * 16;
  const int ntiles = 2 * bt_h + 2;
  const int lt_ntiles = 2 * bt_l + 2;

  const float t = exp2f(-(float)(5 + h));  // 1-gamma (exact)
  const float lng = log1pf(-t);            // ln(gamma)
  const float log2g = lng * 1.44269504088896340736f;

  float rfh[4], rfl[4];
#pragma unroll
  for (int r = 0; r < 4; ++r) {
    int mh = m0h + quad * 4 + r;
    int ml = m0l + quad * 4 + r;
    rfh[r] = exp2f((float)mh * log2g) *
             rsqrtf(-expm1f((float)(mh + 1) * lng) / t);
    rfl[r] = exp2f((float)ml * log2g) *
             rsqrtf(-expm1f((float)(ml + 1) * lng) / t);
  }
  const float gstep = exp2f(-32.0f * log2g);      // gamma^-32
  const float cf0 = exp2f(-(float)l16 * log2g);   // gamma^-l16
  const float cf1 = cf0 * exp2f(-16.0f * log2g);  // gamma^-(16+l16)

  const size_t qoffh = ((size_t)bh * SEQ + m0h + l16) * KD;
  const size_t qoffl = ((size_t)bh * SEQ + m0l + l16) * KD;
  bf16x8 aq0h_h = *(const bf16x8*)&qh[qoffh + quad * 8];
  bf16x8 aq1h_h = *(const bf16x8*)&qh[qoffh + 32 + quad * 8];
  bf16x8 aq0l_h = *(const bf16x8*)&ql[qoffh + quad * 8];
  bf16x8 aq1l_h = *(const bf16x8*)&ql[qoffh + 32 + quad * 8];
  bf16x8 aq0h_l = *(const bf16x8*)&qh[qoffl + quad * 8];
  bf16x8 aq1h_l = *(const bf16x8*)&qh[qoffl + 32 + quad * 8];
  bf16x8 aq0l_l = *(const bf16x8*)&ql[qoffl + quad * 8];
  bf16x8 aq1l_l = *(const bf16x8*)&ql[qoffl + 32 + quad * 8];

  floatx4 oacch[8] = {}, oaccl[8] = {};
  float rsh[4] = {0.f, 0.f, 0.f, 0.f}, rsl[4] = {0.f, 0.f, 0.f, 0.f};

  const bf16* khb = kh + (size_t)bh * SEQ * KD;
  const bf16* klb = kl + (size_t)bh * SEQ * KD;
  const bf16* vbase = vT + (size_t)bh * HD * SEQ;

  auto stage = [&](int nt, int buf) {
    const int n0s = nt * 32;
#pragma unroll
    for (int j = 0; j < 4; ++j) {
      int cc = wave * 4 + j;
      if (cc < 8) {
        const bf16* src = (cc < 4) ? khb : klb;
        bf16* dst = (cc < 4) ? KHs[buf] : KLs[buf];
        int r = ((cc & 3) * 8) + (lane >> 3);
        int s = lane & 7;
        int q = (s - r) & 7;
        ASYNC16(src + (size_t)(n0s + r) * KD + q * 8, &dst[(cc & 3) * 512]);
      } else {
        int r = (cc - 8) * 16 + (lane >> 2);
        int s = lane & 3;
        int q = (s - (r >> 1)) & 3;
        ASYNC16(vbase + (size_t)r * SEQ + n0s + q * 8, &Vs[buf][(cc - 8) * 512]);
      }
    }
  };

  stage(0, 0);
  for (int nt = 0; nt < ntiles; ++nt) {
    const int n0 = nt * 32;
    const int cur = nt & 1;
    asm volatile("s_waitcnt vmcnt(0) lgkmcnt(0)" ::: "memory");
    __syncthreads();
    {
      int pf = (nt + 1 < ntiles) ? nt + 1 : nt;
      stage(pf, cur ^ 1);
    }

    const bool hact = (n0 <= m0h + 15);
    const bool lact = (n0 <= m0l + 15);

    // ---- QK for both stripes, sharing K fragments ----
    floatx4 sch[2], scl[2];
#pragma unroll
    for (int hh = 0; hh < 2; ++hh) {
      int krow = hh * 16 + l16;
      int c0 = ((quad + krow) & 7) * 8;
      int c1 = ((quad + 4 + krow) & 7) * 8;
      bf16x8 bkh0 = *(const bf16x8*)&KHs[cur][krow * 64 + c0];
      bf16x8 bkh1 = *(const bf16x8*)&KHs[cur][krow * 64 + c1];
      bf16x8 bkl0 = *(const bf16x8*)&KLs[cur][krow * 64 + c0];
      bf16x8 bkl1 = *(const bf16x8*)&KLs[cur][krow * 64 + c1];
      if (hact) {
        floatx4 z1 = {0.f, 0.f, 0.f, 0.f}, z2 = z1, z3 = z1;
        z1 = __builtin_amdgcn_mfma_f32_16x16x32_bf16(aq0h_h, bkh0, z1, 0, 0, 0);
        z2 = __builtin_amdgcn_mfma_f32_16x16x32_bf16(aq0l_h, bkh0, z2, 0, 0, 0);
        z3 = __builtin_amdgcn_mfma_f32_16x16x32_bf16(aq0h_h, bkl0, z3, 0, 0, 0);
        z1 = __builtin_amdgcn_mfma_f32_16x16x32_bf16(aq1h_h, bkh1, z1, 0, 0, 0);
        z2 = __builtin_amdgcn_mfma_f32_16x16x32_bf16(aq1l_h, bkh1, z2, 0, 0, 0);
        z3 = __builtin_amdgcn_mfma_f32_16x16x32_bf16(aq1h_h, bkl1, z3, 0, 0, 0);
        sch[hh] = z1 + z2 + z3;
      }
      if (lact) {
        floatx4 z1 = {0.f, 0.f, 0.f, 0.f}, z2 = z1, z3 = z1;
        z1 = __builtin_amdgcn_mfma_f32_16x16x32_bf16(aq0h_l, bkh0, z1, 0, 0, 0);
        z2 = __builtin_amdgcn_mfma_f32_16x16x32_bf16(aq0l_l, bkh0, z2, 0, 0, 0);
        z3 = __builtin_amdgcn_mfma_f32_16x16x32_bf16(aq0h_l, bkl0, z3, 0, 0, 0);
        z1 = __builtin_amdgcn_mfma_f32_16x16x32_bf16(aq1h_l, bkh1, z1, 0, 0, 0);
        z2 = __builtin_amdgcn_mfma_f32_16x16x32_bf16(aq1l_l, bkh1, z2, 0, 0, 0);
        z3 = __builtin_amdgcn_mfma_f32_16x16x32_bf16(aq1h_l, bkl1, z3, 0, 0, 0);
        scl[hh] = z1 + z2 + z3;
      }
    }

    // ---- decay mask + row sums + stage P (both stripes), one fence ----
#pragma unroll
    for (int hh = 0; hh < 2; ++hh) {
      float cf = hh ? cf1 : cf0;
#pragma unroll
      for (int r = 0; r < 4; ++r) {
        int n = n0 + hh * 16 + l16;
        if (hact) {
          int m = m0h + quad * 4 + r;
          float p = (m >= n) ? sch[hh][r] * rfh[r] * cf : 0.f;
          rsh[r] += p;
          Plh[wave][(quad * 4 + r) * 32 + hh * 16 + l16] = f2b(p);
        }
        if (lact) {
          int m = m0l + quad * 4 + r;
          float p = (m >= n) ? scl[hh][r] * rfl[r] * cf : 0.f;
          rsl[r] += p;
          Pll[wave][(quad * 4 + r) * 32 + hh * 16 + l16] = f2b(p);
        }
      }
    }
#pragma unroll
    for (int r = 0; r < 4; ++r) {
      rfh[r] *= gstep;
      if (nt + 1 < lt_ntiles) rfl[r] *= gstep;
    }

    asm volatile("s_waitcnt lgkmcnt(0)" ::: "memory");
    bf16x8 pah, pal;
    if (hact) pah = *(const bf16x8*)&Plh[wave][l16 * 32 + quad * 8];
    if (lact) pal = *(const bf16x8*)&Pll[wave][l16 * 32 + quad * 8];

    // ---- PV for both stripes, sharing V fragments ----
#pragma unroll
    for (int dt = 0; dt < 8; ++dt) {
      int vrow = dt * 16 + l16;
      bf16x8 bv = *(const bf16x8*)&Vs[cur][vrow * 32 + ((quad + (vrow >> 1)) & 3) * 8];
      if (hact)
        oacch[dt] = __builtin_amdgcn_mfma_f32_16x16x32_bf16(pah, bv, oacch[dt], 0, 0, 0);
      if (lact)
        oaccl[dt] = __builtin_amdgcn_mfma_f32_16x16x32_bf16(pal, bv, oaccl[dt], 0, 0, 0);
    }
  }

  // ---- epilogue: denom clip, groupnorm(128), silu gate — per stripe ----
  auto finalize = [&](floatx4* oacc, float* rowsum, int m0) {
    float inv_den[4];
#pragma unroll
    for (int r = 0; r < 4; ++r) {
      float v = rowsum[r];
      v += __shfl_xor(v, 1);
      v += __shfl_xor(v, 2);
      v += __shfl_xor(v, 4);
      v += __shfl_xor(v, 8);
      inv_den[r] = 1.0f / fmaxf(fabsf(v), 1.0f);
    }
    float s1[4] = {}, s2[4] = {};
#pragma unroll
    for (int dt = 0; dt < 8; ++dt) {
#pragma unroll
      for (int r = 0; r < 4; ++r) {
        float v = oacc[dt][r] * inv_den[r];
        oacc[dt][r] = v;
        s1[r] += v;
        s2[r] += v * v;
      }
    }
    float mean[4], istd[4];
#pragma unroll
    for (int r = 0; r < 4; ++r) {
      float a = s1[r], q2 = s2[r];
      a += __shfl_xor(a, 1); a += __shfl_xor(a, 2);
      a += __shfl_xor(a, 4); a += __shfl_xor(a, 8);
      q2 += __shfl_xor(q2, 1); q2 += __shfl_xor(q2, 2);
      q2 += __shfl_xor(q2, 4); q2 += __shfl_xor(q2, 8);
      mean[r] = a * (1.0f / 128.0f);
      float var = q2 * (1.0f / 128.0f) - mean[r] * mean[r];
      istd[r] = rsqrtf(fmaxf(var, 0.0f) + 1e-5f);
    }
#pragma unroll
    for (int dt = 0; dt < 8; ++dt) {
#pragma unroll
      for (int r = 0; r < 4; ++r) {
        int m = m0 + quad * 4 + r;
        int col = h * HD + dt * 16 + l16;
        float v = (oacc[dt][r] - mean[r]) * istd[r];
        float gv = g[((size_t)b * SEQ + m) * 2048 + col];
        float sg = gv / (1.0f + expf(-gv));
        gated[((size_t)b * SEQ + m) * 2048 + col] = f2b(sg * v);
      }
    }
  };
  finalize(oacch, rsh, m0h);
  finalize(oaccl, rsl, m0l);
}

// ---------------- launch ----------------
extern "C" void kernel_launch(void* const* d_in, const int* in_sizes, int n_in,
                              void* d_out, int out_size, void* d_ws,
                              size_t ws_size, hipStream_t stream) {
  const float* x   = (const float*)d_in[0];
  const float* q_w = (const float*)d_in[1];
  const float* q_b = (const float*)d_in[2];
  const float* k_w = (const float*)d_in[3];
  const float* k_b = (const float*)d_in[4];
  const float* v_w = (const float*)d_in[5];
  const float* v_b = (const float*)d_in[6];
  const float* g_w = (const float*)d_in[7];
  const float* g_b = (const float*)d_in[8];
  const float* o_w = (const float*)d_in[9];
  const float* o_b = (const float*)d_in[10];

  char* ws = (char*)d_ws;
  bf16* Wt    = (bf16*)ws; ws += (size_t)6144 * 1024 * 2;
  bf16* oT    = (bf16*)ws; ws += (size_t)1024 * 2048 * 2;
  bf16* xb    = (bf16*)ws; ws += (size_t)4096 * 1024 * 2;
  float* Cqk  = (float*)ws; ws += (size_t)4096 * 2048 * 4;
  bf16* qhb   = (bf16*)ws; ws += (size_t)32 * 2048 * 64 * 2;
  bf16* qlb   = (bf16*)ws; ws += (size_t)32 * 2048 * 64 * 2;
  bf16* khb   = (bf16*)ws; ws += (size_t)32 * 2048 * 64 * 2;
  bf16* klb   = (bf16*)ws; ws += (size_t)32 * 2048 * 64 * 2;
  bf16* vTb   = (bf16*)ws; ws += (size_t)32 * 128 * 2048 * 2;
  float* gbuf = (float*)ws; ws += (size_t)2 * 2048 * 2048 * 4;
  bf16* gated = (bf16*)ws; ws += (size_t)4096 * 2048 * 2;
  // vbuf aliases gated: vbuf lives GEMM1->vtrans, gated lives retention->GEMM2
  bf16* vbuf  = gated;

  convert_k<<<(4096 * 1024 / 4) / 256, 256, 0, stream>>>(x, xb);

  dim3 tb(32, 8);
  transpose_k<<<dim3(1024 / 32, 1024 / 32), tb, 0, stream>>>(q_w, Wt, 1024, 1024);
  transpose_k<<<dim3(1024 / 32, 1024 / 32), tb, 0, stream>>>(k_w, Wt + (size_t)1024 * 1024, 1024, 1024);
  transpose_k<<<dim3(2048 / 32, 1024 / 32), tb, 0, stream>>>(v_w, Wt + (size_t)2048 * 1024, 1024, 2048);
  transpose_k<<<dim3(2048 / 32, 1024 / 32), tb, 0, stream>>>(g_w, Wt + (size_t)4096 * 1024, 1024, 2048);
  transpose_k<<<dim3(1024 / 32, 2048 / 32), tb, 0, stream>>>(o_w, oT, 2048, 1024);

  gemm_bt<128, 128, 1024, 0><<<dim3(6144 / 128, 4096 / 128), 256, 0, stream>>>(
      xb, Wt, 6144, q_b, k_b, v_b, g_b, Cqk, vbuf, gbuf, nullptr);

  vtrans_k<<<dim3(64, 64, B_SZ), tb, 0, stream>>>(vbuf, vTb);

  router_k<<<(4096 * 1024) / 256, 256, 0, stream>>>(Cqk, qhb, qlb, khb, klb);

  retention_k<<<dim3(16, NH, B_SZ), 256, 0, stream>>>(
      qhb, qlb, khb, klb, vTb, gbuf, gated);

  gemm_bt<128, 64, 2048, 1><<<dim3(1024 / 64, 4096 / 128), 256, 0, stream>>>(
      gated, oT, 1024, o_b, nullptr, nullptr, nullptr, nullptr, nullptr,
      nullptr, (float*)d_out);
}